// Round 6
// baseline (455.900 us; speedup 1.0000x reference)
//
#include <hip/hip_runtime.h>
#include <hip/hip_bf16.h>

#define BB 32
#define SS 4096
#define HH 512
#define EE 512
#define NCH 64          // 64-row s-chunks per b
#define CPB 4           // chunks per block (persistent sweep)
#define NEGV -1000000000.0f

using float4v = __attribute__((ext_vector_type(4))) float;
using short8v = __attribute__((ext_vector_type(8))) short;

__device__ inline unsigned short f2bf(float x) {
    union { float f; unsigned int u; } c; c.f = x;
    unsigned int r = c.u + 0x7FFFu + ((c.u >> 16) & 1u);  // RNE
    return (unsigned short)(r >> 16);
}
__device__ inline float bf2f(unsigned short s) {
    union { float f; unsigned int u; } c; c.u = ((unsigned int)s) << 16;
    return c.f;
}
__device__ inline unsigned int pk2bf(float a, float b) {  // packed RNE cvt (1 inst)
    union { __hip_bfloat162 h; unsigned int u; } c;
    c.h = __float22bfloat162_rn(float2{a, b});
    return c.u;
}

// Partial q-projection: grid (8, B); atomicAdd into qp (bq+bk folded later).
__global__ void qproj_kernel(const float* __restrict__ query, const float* __restrict__ Wq,
                             float* __restrict__ qp) {
    __shared__ float qs[64];
    int b = blockIdx.y, e0 = blockIdx.x * 64, t = threadIdx.x;  // 256 threads
    if (t < 64) qs[t] = query[b * HH + e0 + t];
    __syncthreads();
    int h0 = t, h1 = t + 256;
    float a0 = 0.f, a1 = 0.f;
    #pragma unroll 8
    for (int e = 0; e < 64; ++e) {
        float q = qs[e];
        a0 += q * Wq[(size_t)(e0 + e) * HH + h0];
        a1 += q * Wq[(size_t)(e0 + e) * HH + h1];
    }
    atomicAdd(&qp[b * HH + h0], a0);
    atomicAdd(&qp[b * HH + h1], a1);
}

// Repack Wk (E,H) fp32 -> fragment-linear bf16: frag[ks][nt][lane] (16B/lane burst).
__global__ void wkt_kernel(const float* __restrict__ Wk, unsigned short* __restrict__ WkT) {
    int g = blockIdx.x * 256 + threadIdx.x;
    int lane = g & 63, nt = (g >> 6) & 31, ks = g >> 11;
    int lq = lane >> 4, lr = lane & 15;
    int h = nt * 16 + lr;
    int e0 = ks * 32 + lq * 8;
    short8v o;
    #pragma unroll
    for (int j = 0; j < 8; ++j) o[j] = (short)f2bf(Wk[(size_t)(e0 + j) * HH + h]);
    *(short8v*)(WkT + (size_t)g * 8) = o;
}

// Persistent fused kernel: grid (NCH/CPB=16, B) = 512 blocks (2/CU), 1024 threads.
// Each block sweeps 4 consecutive 64-row chunks; next chunk's keys are loaded to
// registers after the K-loop so HBM latency hides under epilogue+context.
__launch_bounds__(1024, 4)
__global__ void fused_kernel(const float* __restrict__ keys, const unsigned short* __restrict__ WkT,
                             const float* __restrict__ qp, const float* __restrict__ bq,
                             const float* __restrict__ bk, const float* __restrict__ v,
                             const float* __restrict__ bv, const int* __restrict__ mask,
                             float* __restrict__ scores, float* __restrict__ part,
                             float* __restrict__ marr, float* __restrict__ larr) {
    constexpr int LDK = EE + 8;                 // 520 shorts; lr-stride = 4 banks -> 2-way (free)
    __shared__ unsigned short klds[64 * LDK];   // 66.5 KB
    __shared__ float qp_lds[HH];
    __shared__ float v_lds[HH];
    __shared__ float red[16][64];               // reused as octx[1024] in context phase
    __shared__ float p_lds[64];
    float* octx = &red[0][0];
    int b = blockIdx.y, c0 = blockIdx.x * CPB;
    int tid = threadIdx.x;

    for (int i = tid; i < HH; i += 1024) {
        qp_lds[i] = qp[b * HH + i] + bq[i] + bk[i];
        v_lds[i] = v[i];
    }

    int w = tid >> 6, lane = tid & 63;
    int lq = lane >> 4, lr = lane & 15;
    int nt0 = w * 2;                            // wave owns 2 n-tiles (disjoint across 16 waves)
    const short8v* Wf = (const short8v*)WkT;

    // initial stage of chunk c0: 8 float4/thread -> bf16 LDS
    {
        const float4v* ksrc = (const float4v*)(keys + ((size_t)b * SS + c0 * 64) * EE);
        float4v kv[8];
        #pragma unroll
        for (int p = 0; p < 8; ++p) kv[p] = ksrc[tid + p * 1024];
        #pragma unroll
        for (int p = 0; p < 8; ++p) {
            int idx = tid + p * 1024, row = idx >> 7, c4 = idx & 127;
            unsigned int u0 = pk2bf(kv[p].x, kv[p].y), u1 = pk2bf(kv[p].z, kv[p].w);
            *(unsigned int*)(&klds[row * LDK + c4 * 4]) = u0;
            *(unsigned int*)(&klds[row * LDK + c4 * 4 + 2]) = u1;
        }
    }
    __syncthreads();

    for (int i = 0; i < CPB; ++i) {
        int c = c0 + i, s0 = c * 64;

        float4v acc[4][2];
        #pragma unroll
        for (int m = 0; m < 4; ++m)
            #pragma unroll
            for (int j = 0; j < 2; ++j) acc[m][j] = (float4v){0.f, 0.f, 0.f, 0.f};

        // barrier-free K-loop: B-frags stream from L2 (coalesced 1KB bursts), A from LDS
        #pragma unroll 2
        for (int ksg = 0; ksg < 16; ++ksg) {
            short8v bfrag[2];
            #pragma unroll
            for (int j = 0; j < 2; ++j)
                bfrag[j] = Wf[((size_t)ksg * 32 + nt0 + j) * 64 + lane];
            #pragma unroll
            for (int m = 0; m < 4; ++m) {
                short8v afrag = *(const short8v*)(&klds[(m * 16 + lr) * LDK + ksg * 32 + lq * 8]);
                #pragma unroll
                for (int j = 0; j < 2; ++j)
                    acc[m][j] = __builtin_amdgcn_mfma_f32_16x16x32_bf16(afrag, bfrag[j], acc[m][j], 0, 0, 0);
            }
        }

        // prefetch next chunk's keys NOW: lands during epilogue+context (no waitcnt until cvt)
        float4v kreg[8];
        if (i < CPB - 1) {
            const float4v* knxt = (const float4v*)(keys + ((size_t)b * SS + (c + 1) * 64) * EE);
            #pragma unroll
            for (int p = 0; p < 8; ++p) kreg[p] = knxt[tid + p * 1024];
        }

        // tanh epilogue: part += v[h] - 2 v[h] / (e^{2x} + 1)  (== v[h]*tanh(x), clamp-free)
        float part_r[4][4];
        #pragma unroll
        for (int m = 0; m < 4; ++m)
            #pragma unroll
            for (int r = 0; r < 4; ++r) part_r[m][r] = 0.f;
        #pragma unroll
        for (int j = 0; j < 2; ++j) {
            int h = (nt0 + j) * 16 + lr;
            float vj = v_lds[h], qj = qp_lds[h], vj2 = -2.f * vj;
            #pragma unroll
            for (int m = 0; m < 4; ++m) {
                #pragma unroll
                for (int r = 0; r < 4; ++r) {
                    float x = qj + acc[m][j][r];
                    float rr = __frcp_rn(__expf(2.f * x) + 1.f);
                    part_r[m][r] += __builtin_fmaf(vj2, rr, vj);
                }
            }
        }
        #pragma unroll
        for (int m = 0; m < 4; ++m)
            #pragma unroll
            for (int r = 0; r < 4; ++r) {
                float p = part_r[m][r];
                p += __shfl_xor(p, 1, 16);
                p += __shfl_xor(p, 2, 16);
                p += __shfl_xor(p, 4, 16);
                p += __shfl_xor(p, 8, 16);
                part_r[m][r] = p;
            }
        if (lr == 0) {
            #pragma unroll
            for (int m = 0; m < 4; ++m)
                #pragma unroll
                for (int r = 0; r < 4; ++r)
                    red[w][m * 16 + lq * 4 + r] = part_r[m][r];
        }
        __syncthreads();

        // wave 0: final score, mask, chunk-local softmax stats
        if (tid < 64) {
            float sc = bv[0];
            #pragma unroll
            for (int ww = 0; ww < 16; ++ww) sc += red[ww][tid];
            int s = s0 + tid;
            if (mask[b * SS + s] == 0) sc = NEGV;
            scores[b * SS + s] = sc;
            float mv = sc;
            #pragma unroll
            for (int off = 1; off < 64; off <<= 1) mv = fmaxf(mv, __shfl_xor(mv, off));
            float pe = __expf(sc - mv);
            float ls = pe;
            #pragma unroll
            for (int off = 1; off < 64; off <<= 1) ls += __shfl_xor(ls, off);
            p_lds[tid] = pe;
            if (tid == 0) { marr[b * NCH + c] = mv; larr[b * NCH + c] = ls; }
        }
        __syncthreads();

        // context partial from LDS keys tile, split 2-ways over s
        {
            int e = tid & 511, sh = tid >> 9;
            float o = 0.f;
            #pragma unroll 8
            for (int s = sh * 32; s < sh * 32 + 32; ++s)
                o += p_lds[s] * bf2f(klds[s * LDK + e]);
            octx[tid] = o;  // octx aliases red (safe: red consumed above, barrier passed)
        }
        __syncthreads();
        if (tid < 512)
            part[((size_t)b * NCH + c) * EE + tid] = octx[tid] + octx[tid + 512];

        // store next chunk into klds (prefetched regs; klds reads all done at last barrier)
        if (i < CPB - 1) {
            #pragma unroll
            for (int p = 0; p < 8; ++p) {
                int idx = tid + p * 1024, row = idx >> 7, c4 = idx & 127;
                unsigned int u0 = pk2bf(kreg[p].x, kreg[p].y), u1 = pk2bf(kreg[p].z, kreg[p].w);
                *(unsigned int*)(&klds[row * LDK + c4 * 4]) = u0;
                *(unsigned int*)(&klds[row * LDK + c4 * 4 + 2]) = u1;
            }
            __syncthreads();
        }
    }
}

// Merge chunk partials; grid (4, B): x==0 writes ctx, all x write attn slices.
__global__ void finalize_kernel(const float* __restrict__ scores, const float* __restrict__ part,
                                const float* __restrict__ marr, const float* __restrict__ larr,
                                float* __restrict__ ctx, float* __restrict__ attn) {
    __shared__ float wgt[NCH];
    __shared__ float Ms, Ls;
    int b = blockIdx.y, px = blockIdx.x, t = threadIdx.x;  // 512 threads
    if (t < NCH) {
        float m = marr[b * NCH + t], l = larr[b * NCH + t];
        float M = m;
        #pragma unroll
        for (int off = 1; off < 64; off <<= 1) M = fmaxf(M, __shfl_xor(M, off));
        float wq = __expf(m - M);
        float L = wq * l;
        #pragma unroll
        for (int off = 1; off < 64; off <<= 1) L += __shfl_xor(L, off);
        wgt[t] = wq;
        if (t == 0) { Ms = M; Ls = L; }
    }
    __syncthreads();
    float M = Ms, invL = 1.f / Ls;
    if (px == 0) {
        float o = 0.f;
        #pragma unroll 8
        for (int cc = 0; cc < NCH; ++cc)
            o += wgt[cc] * part[((size_t)b * NCH + cc) * EE + t];
        ctx[b * EE + t] = o * invL;
    }
    int s0 = px * 1024;
    attn[b * SS + s0 + t]       = __expf(scores[b * SS + s0 + t] - M) * invL;
    attn[b * SS + s0 + t + 512] = __expf(scores[b * SS + s0 + t + 512] - M) * invL;
}

extern "C" void kernel_launch(void* const* d_in, const int* in_sizes, int n_in,
                              void* d_out, int out_size, void* d_ws, size_t ws_size,
                              hipStream_t stream) {
    const float* query = (const float*)d_in[0];
    const float* keys  = (const float*)d_in[1];
    const int*   mask  = (const int*)d_in[2];
    const float* Wq    = (const float*)d_in[3];
    const float* bq    = (const float*)d_in[4];
    const float* Wk    = (const float*)d_in[5];
    const float* bk    = (const float*)d_in[6];
    const float* v     = (const float*)d_in[7];
    const float* bv    = (const float*)d_in[8];

    float* out  = (float*)d_out;
    float* ctx  = out;            // (B, E)
    float* attn = out + BB * EE;  // (B, S)

    char* ws = (char*)d_ws;
    float* qp           = (float*)ws;                         // 65536 B
    unsigned short* WkT = (unsigned short*)(ws + 65536);      // 524288 B
    float* scores       = (float*)(ws + 589824);              // 524288 B
    float* part         = (float*)(ws + 1114112);             // 4194304 B
    float* marr         = (float*)(ws + 5308416);             // 8192 B
    float* larr         = (float*)(ws + 5316608);             // 8192 B

    hipMemsetAsync(qp, 0, BB * HH * sizeof(float), stream);
    qproj_kernel<<<dim3(8, BB), 256, 0, stream>>>(query, Wq, qp);
    wkt_kernel<<<128, 256, 0, stream>>>(Wk, WkT);
    fused_kernel<<<dim3(NCH / CPB, BB), 1024, 0, stream>>>(keys, WkT, qp, bq, bk, v, bv, mask,
                                                           scores, part, marr, larr);
    finalize_kernel<<<dim3(4, BB), 512, 0, stream>>>(scores, part, marr, larr, ctx, attn);
}

// Round 7
// 426.980 us; speedup vs baseline: 1.0677x; 1.0677x over previous
//
#include <hip/hip_runtime.h>
#include <hip/hip_bf16.h>

#define BB 32
#define SS 4096
#define HH 512
#define EE 512
#define NCH 64          // 64-row s-chunks per b
#define NEGV -1000000000.0f

using float4v = __attribute__((ext_vector_type(4))) float;
using short8v = __attribute__((ext_vector_type(8))) short;

#if defined(__has_builtin)
#if __has_builtin(__builtin_amdgcn_sched_barrier)
#define SCHED_FENCE() __builtin_amdgcn_sched_barrier(0)
#endif
#endif
#ifndef SCHED_FENCE
#define SCHED_FENCE()
#endif

__device__ inline unsigned short f2bf(float x) {
    union { float f; unsigned int u; } c; c.f = x;
    unsigned int r = c.u + 0x7FFFu + ((c.u >> 16) & 1u);  // RNE
    return (unsigned short)(r >> 16);
}
__device__ inline float bf2f(unsigned short s) {
    union { float f; unsigned int u; } c; c.u = ((unsigned int)s) << 16;
    return c.f;
}
__device__ inline unsigned int pk2bf(float a, float b) {  // packed RNE cvt
    union { __hip_bfloat162 h; unsigned int u; } c;
    c.h = __float22bfloat162_rn(float2{a, b});
    return c.u;
}

// Partial q-projection: grid (8, B); atomicAdd into qp (bq+bk folded later).
__global__ void qproj_kernel(const float* __restrict__ query, const float* __restrict__ Wq,
                             float* __restrict__ qp) {
    __shared__ float qs[64];
    int b = blockIdx.y, e0 = blockIdx.x * 64, t = threadIdx.x;  // 256 threads
    if (t < 64) qs[t] = query[b * HH + e0 + t];
    __syncthreads();
    int h0 = t, h1 = t + 256;
    float a0 = 0.f, a1 = 0.f;
    #pragma unroll 8
    for (int e = 0; e < 64; ++e) {
        float q = qs[e];
        a0 += q * Wq[(size_t)(e0 + e) * HH + h0];
        a1 += q * Wq[(size_t)(e0 + e) * HH + h1];
    }
    atomicAdd(&qp[b * HH + h0], a0);
    atomicAdd(&qp[b * HH + h1], a1);
}

// Repack Wk (E,H) fp32 -> fragment-linear bf16: frag[ks][nt][lane] (16B/lane burst).
__global__ void wkt_kernel(const float* __restrict__ Wk, unsigned short* __restrict__ WkT) {
    int g = blockIdx.x * 256 + threadIdx.x;
    int lane = g & 63, nt = (g >> 6) & 31, ks = g >> 11;
    int lq = lane >> 4, lr = lane & 15;
    int h = nt * 16 + lr;
    int e0 = ks * 32 + lq * 8;
    short8v o;
    #pragma unroll
    for (int j = 0; j < 8; ++j) o[j] = (short)f2bf(Wk[(size_t)(e0 + j) * HH + h]);
    *(short8v*)(WkT + (size_t)g * 8) = o;
}

// Fused scores + online-softmax stats + context partial. grid (NCH, B), 512 thr.
// Keys tile staged in four 128-col segments: segment q+1's HBM loads are issued
// (and pinned by a sched fence) before segment q's MFMAs, so staging latency
// hides under compute. Tile retained in LDS for the context pass.
__launch_bounds__(512, 4)
__global__ void fused_kernel(const float* __restrict__ keys, const unsigned short* __restrict__ WkT,
                             const float* __restrict__ qp, const float* __restrict__ bq,
                             const float* __restrict__ bk, const float* __restrict__ v,
                             const float* __restrict__ bv, const int* __restrict__ mask,
                             float* __restrict__ scores, float* __restrict__ part,
                             float* __restrict__ marr, float* __restrict__ larr) {
    constexpr int LDK = EE + 8;                 // 520 shorts, 1040B row stride
    __shared__ unsigned short klds[64 * LDK];   // 66.5 KB
    __shared__ float qp_lds[HH];
    __shared__ float v_lds[HH];
    __shared__ float red[8][64];
    __shared__ float p_lds[64];
    int b = blockIdx.y, c = blockIdx.x, s0 = c * 64;
    int tid = threadIdx.x;

    for (int i = tid; i < HH; i += 512) {
        qp_lds[i] = qp[b * HH + i] + bq[i] + bk[i];
        v_lds[i] = v[i];
    }

    const float4v* ksrc = (const float4v*)(keys + ((size_t)b * SS + s0) * EE);
    // segment geometry: seg q = cols [q*128, q*128+128); 2048 float4/seg, 4/thread
    int srow = tid >> 3 << 0;  // placeholder to keep compiler honest
    (void)srow;

    float4v kv[4];
    #pragma unroll
    for (int p = 0; p < 4; ++p) {
        int idx = tid + p * 512;
        kv[p] = ksrc[(size_t)(idx >> 5) * 128 + (idx & 31)];
    }
    #pragma unroll
    for (int p = 0; p < 4; ++p) {
        int idx = tid + p * 512, row = idx >> 5, c4 = idx & 31;
        *(unsigned int*)(&klds[row * LDK + c4 * 4])     = pk2bf(kv[p].x, kv[p].y);
        *(unsigned int*)(&klds[row * LDK + c4 * 4 + 2]) = pk2bf(kv[p].z, kv[p].w);
    }
    __syncthreads();

    int w = tid >> 6, lane = tid & 63;
    int lq = lane >> 4, lr = lane & 15;
    int nt0 = w * 4;

    float4v acc[4][4];
    #pragma unroll
    for (int m = 0; m < 4; ++m)
        #pragma unroll
        for (int j = 0; j < 4; ++j) acc[m][j] = (float4v){0.f, 0.f, 0.f, 0.f};

    const short8v* Wf = (const short8v*)WkT;

    for (int q = 0; q < 4; ++q) {
        if (q < 3) {  // issue next segment's HBM loads; fence pins them above the MFMAs
            #pragma unroll
            for (int p = 0; p < 4; ++p) {
                int idx = tid + p * 512;
                kv[p] = ksrc[(size_t)(idx >> 5) * 128 + (q + 1) * 32 + (idx & 31)];
            }
        }
        SCHED_FENCE();
        #pragma unroll
        for (int ksl = 0; ksl < 4; ++ksl) {
            int kq = q * 4 + ksl;
            short8v bfrag[4];
            #pragma unroll
            for (int j = 0; j < 4; ++j)
                bfrag[j] = Wf[((size_t)kq * 32 + nt0 + j) * 64 + lane];
            #pragma unroll
            for (int m = 0; m < 4; ++m) {
                short8v afrag = *(const short8v*)(&klds[(m * 16 + lr) * LDK + kq * 32 + lq * 8]);
                #pragma unroll
                for (int j = 0; j < 4; ++j)
                    acc[m][j] = __builtin_amdgcn_mfma_f32_16x16x32_bf16(afrag, bfrag[j], acc[m][j], 0, 0, 0);
            }
        }
        if (q < 3) {  // cvt+store next segment (LDS range disjoint from this segment's reads)
            #pragma unroll
            for (int p = 0; p < 4; ++p) {
                int idx = tid + p * 512, row = idx >> 5, c4 = (q + 1) * 32 + (idx & 31);
                *(unsigned int*)(&klds[row * LDK + c4 * 4])     = pk2bf(kv[p].x, kv[p].y);
                *(unsigned int*)(&klds[row * LDK + c4 * 4 + 2]) = pk2bf(kv[p].z, kv[p].w);
            }
            __syncthreads();
        }
    }

    // tanh epilogue: part += v[h] - 2 v[h] / (e^{2x}+1)   (== v[h]*tanh(x), clamp-free)
    float part_r[4][4];
    #pragma unroll
    for (int m = 0; m < 4; ++m)
        #pragma unroll
        for (int r = 0; r < 4; ++r) part_r[m][r] = 0.f;
    #pragma unroll
    for (int j = 0; j < 4; ++j) {
        int h = (nt0 + j) * 16 + lr;
        float vj = v_lds[h], qj = qp_lds[h], vj2 = -2.f * vj;
        #pragma unroll
        for (int m = 0; m < 4; ++m) {
            #pragma unroll
            for (int r = 0; r < 4; ++r) {
                float x = qj + acc[m][j][r];
                float rr = __frcp_rn(__expf(2.f * x) + 1.f);
                part_r[m][r] += __builtin_fmaf(vj2, rr, vj);
            }
        }
    }
    #pragma unroll
    for (int m = 0; m < 4; ++m)
        #pragma unroll
        for (int r = 0; r < 4; ++r) {
            float p = part_r[m][r];
            p += __shfl_xor(p, 1, 16);
            p += __shfl_xor(p, 2, 16);
            p += __shfl_xor(p, 4, 16);
            p += __shfl_xor(p, 8, 16);
            part_r[m][r] = p;
        }
    if (lr == 0) {
        #pragma unroll
        for (int m = 0; m < 4; ++m)
            #pragma unroll
            for (int r = 0; r < 4; ++r)
                red[w][m * 16 + lq * 4 + r] = part_r[m][r];
    }
    __syncthreads();

    // wave 0: final score, mask, chunk-local softmax stats
    if (tid < 64) {
        float sc = red[0][tid] + red[1][tid] + red[2][tid] + red[3][tid]
                 + red[4][tid] + red[5][tid] + red[6][tid] + red[7][tid] + bv[0];
        int s = s0 + tid;
        if (mask[b * SS + s] == 0) sc = NEGV;
        scores[b * SS + s] = sc;
        float mv = sc;
        #pragma unroll
        for (int off = 1; off < 64; off <<= 1) mv = fmaxf(mv, __shfl_xor(mv, off));
        float pe = __expf(sc - mv);
        float ls = pe;
        #pragma unroll
        for (int off = 1; off < 64; off <<= 1) ls += __shfl_xor(ls, off);
        p_lds[tid] = pe;
        if (tid == 0) { marr[b * NCH + c] = mv; larr[b * NCH + c] = ls; }
    }
    __syncthreads();

    // context partial from the retained LDS tile: o[e] = sum_s p[s]*keys[s][e]
    {
        float o0 = 0.f, o1 = 0.f;
        #pragma unroll 8
        for (int s = 0; s < 32; ++s) {
            o0 += p_lds[s]      * bf2f(klds[s * LDK + tid]);
            o1 += p_lds[s + 32] * bf2f(klds[(s + 32) * LDK + tid]);
        }
        part[((size_t)b * NCH + c) * EE + tid] = o0 + o1;
    }
}

// Merge chunk partials; grid (4, B): x==0 writes ctx, all x write attn slices.
__global__ void finalize_kernel(const float* __restrict__ scores, const float* __restrict__ part,
                                const float* __restrict__ marr, const float* __restrict__ larr,
                                float* __restrict__ ctx, float* __restrict__ attn) {
    __shared__ float wgt[NCH];
    __shared__ float Ms, Ls;
    int b = blockIdx.y, px = blockIdx.x, t = threadIdx.x;  // 512 threads
    if (t < NCH) {
        float m = marr[b * NCH + t], l = larr[b * NCH + t];
        float M = m;
        #pragma unroll
        for (int off = 1; off < 64; off <<= 1) M = fmaxf(M, __shfl_xor(M, off));
        float wq = __expf(m - M);
        float L = wq * l;
        #pragma unroll
        for (int off = 1; off < 64; off <<= 1) L += __shfl_xor(L, off);
        wgt[t] = wq;
        if (t == 0) { Ms = M; Ls = L; }
    }
    __syncthreads();
    float M = Ms, invL = 1.f / Ls;
    if (px == 0) {
        float o = 0.f;
        #pragma unroll 8
        for (int cc = 0; cc < NCH; ++cc)
            o += wgt[cc] * part[((size_t)b * NCH + cc) * EE + t];
        ctx[b * EE + t] = o * invL;
    }
    int s0 = px * 1024;
    attn[b * SS + s0 + t]       = __expf(scores[b * SS + s0 + t] - M) * invL;
    attn[b * SS + s0 + t + 512] = __expf(scores[b * SS + s0 + t + 512] - M) * invL;
}

extern "C" void kernel_launch(void* const* d_in, const int* in_sizes, int n_in,
                              void* d_out, int out_size, void* d_ws, size_t ws_size,
                              hipStream_t stream) {
    const float* query = (const float*)d_in[0];
    const float* keys  = (const float*)d_in[1];
    const int*   mask  = (const int*)d_in[2];
    const float* Wq    = (const float*)d_in[3];
    const float* bq    = (const float*)d_in[4];
    const float* Wk    = (const float*)d_in[5];
    const float* bk    = (const float*)d_in[6];
    const float* v     = (const float*)d_in[7];
    const float* bv    = (const float*)d_in[8];

    float* out  = (float*)d_out;
    float* ctx  = out;            // (B, E)
    float* attn = out + BB * EE;  // (B, S)

    char* ws = (char*)d_ws;
    float* qp           = (float*)ws;                         // 65536 B
    unsigned short* WkT = (unsigned short*)(ws + 65536);      // 524288 B
    float* scores       = (float*)(ws + 589824);              // 524288 B
    float* part         = (float*)(ws + 1114112);             // 4194304 B
    float* marr         = (float*)(ws + 5308416);             // 8192 B
    float* larr         = (float*)(ws + 5316608);             // 8192 B

    hipMemsetAsync(qp, 0, BB * HH * sizeof(float), stream);
    qproj_kernel<<<dim3(8, BB), 256, 0, stream>>>(query, Wq, qp);
    wkt_kernel<<<128, 256, 0, stream>>>(Wk, WkT);
    fused_kernel<<<dim3(NCH, BB), 512, 0, stream>>>(keys, WkT, qp, bq, bk, v, bv, mask,
                                                    scores, part, marr, larr);
    finalize_kernel<<<dim3(4, BB), 512, 0, stream>>>(scores, part, marr, larr, ctx, attn);
}